// Round 13
// baseline (443.637 us; speedup 1.0000x reference)
//
#include <hip/hip_runtime.h>
#include <math.h>

#define NPTS  8192
#define INCH  1024
#define FDIM  128
#define KNN   10
#define NCAND 16
#define NNS   16              // nn row stride (padded)
#define STILE 256
#define NT2   (NPTS / STILE)              // 32
#define NBLK2 (NT2 * (NT2 + 1) / 2)       // 528 triangle blocks

typedef __attribute__((ext_vector_type(8))) __bf16          bf16x8;
typedef __attribute__((ext_vector_type(4))) float           f32x4;
typedef __attribute__((ext_vector_type(8))) unsigned short  us8;
typedef __attribute__((ext_vector_type(4))) unsigned short  us4;
typedef __attribute__((ext_vector_type(4))) _Float16        f16x4;

// u32 compare-exchange: a=min, b=max  (v_min_u32 + v_max_u32)
#define CE32(a,b) do { unsigned lo_ = min((a),(b)); unsigned hi_ = max((a),(b)); \
                       (a)=lo_; (b)=hi_; } while(0)

__device__ __forceinline__ unsigned short f2bf(float f) {
    unsigned u = __float_as_uint(f);
    return (unsigned short)((u + 0x7fffu + ((u >> 16) & 1u)) >> 16);
}

// async global->LDS, 16 bytes per lane (dest = wave-uniform base + lane*16)
__device__ __forceinline__ void gload16(const void* g, void* l) {
    __builtin_amdgcn_global_load_lds(
        (const __attribute__((address_space(1))) unsigned int*)g,
        (__attribute__((address_space(3))) unsigned int*)l, 16, 0, 0);
}

// ---------------------------------------------------------------------------
// prep: sq[i] = sum x[i][d]^2 (bit-identical order) AND xb = bf16(x).
// ---------------------------------------------------------------------------
__global__ __launch_bounds__(256) void prep_kernel(const float* __restrict__ x,
                                                   float* __restrict__ sq,
                                                   unsigned short* __restrict__ xb) {
    int wave = threadIdx.x >> 6;
    int lane = threadIdx.x & 63;
    int row  = blockIdx.x * 4 + wave;
    const float4* xr = (const float4*)(x + (size_t)row * INCH);
    unsigned short* xo = xb + (size_t)row * INCH;
    float s = 0.f;
    #pragma unroll
    for (int i = 0; i < 4; ++i) {
        float4 v = xr[lane + i * 64];
        s += v.x * v.x + v.y * v.y + v.z * v.z + v.w * v.w;
        us4 o; o[0] = f2bf(v.x); o[1] = f2bf(v.y); o[2] = f2bf(v.z); o[3] = f2bf(v.w);
        *(us4*)(xo + (size_t)(lane + i * 64) * 4) = o;
    }
    #pragma unroll
    for (int o = 32; o; o >>= 1) s += __shfl_xor(s, o);
    if (lane == 0) sq[row] = s;
}

// ---------------------------------------------------------------------------
// theta transpose+convert: th[K][128] f32 -> out[128][K] bf16 (64x64 LDS tiles)
// ---------------------------------------------------------------------------
__global__ __launch_bounds__(256) void thT_kernel(const float* __restrict__ th,
                                                  unsigned short* __restrict__ out,
                                                  int K) {
    __shared__ unsigned short T[64][68];
    int k0 = blockIdx.x * 64;
    int n0 = blockIdx.y * 64;
    int t = threadIdx.x;
    int r  = t >> 2;
    int cs = (t & 3) * 16;
    const float* src = th + (size_t)(k0 + r) * FDIM + n0 + cs;
    #pragma unroll
    for (int i = 0; i < 4; ++i) {
        float4 v = *(const float4*)(src + i * 4);
        us4 o; o[0] = f2bf(v.x); o[1] = f2bf(v.y); o[2] = f2bf(v.z); o[3] = f2bf(v.w);
        *(us4*)&T[r][cs + i * 4] = o;
    }
    __syncthreads();
    int n  = t >> 2;
    int ks = (t & 3) * 16;
    unsigned short* dst = out + (size_t)(n0 + n) * K + k0 + ks;
    #pragma unroll
    for (int i = 0; i < 16; ++i)
        dst[i] = T[ks + i][n];
}

// ---------------------------------------------------------------------------
// bf16 MFMA distance tile -> f16 ( max(d,0)*0.25 ) matrix.
// Round-13: 256x256 tile, 8 waves (512 thr), wave grid 2x4, 8x4 fragments of
// 16x16x32, BK=32.  Staging per K-step unchanged (32 KB via 4 global_load_lds
// per thread) but 4x MFMA per staged byte -> staging traffic 2.1 GB -> 0.54 GB.
// Simple round-11 barrier schedule (counted-vmcnt reverted: it thrashed L2).
// Pre-swizzled source granules as before; per-element MFMA accumulation order
// bit-identical to rounds 5-12.  Off-diagonal transposed tile written via two
// 128-col LDS passes (recompute h from acc) -> 128B-contiguous global stores.
// ---------------------------------------------------------------------------
union SharedU {
    struct { unsigned short A[2][8192], B[2][8192]; } s;   // 64 KB staging
    _Float16 T[128 * 264];                                  // 67.6 KB transpose
};

template <bool SYM>
__global__ __launch_bounds__(512) void mfma_dist_kernel(const unsigned short* __restrict__ xb,
                                                        const float* __restrict__ sq,
                                                        _Float16* __restrict__ Dh,
                                                        int r0) {
    __shared__ SharedU smem;
    int bx, byy;
    if (SYM) {
        int b = blockIdx.x;
        int t = (b & 7) * (NBLK2 / 8) + (b >> 3);   // XCD swizzle (T1), 528%8==0
        bx = (int)((sqrtf(8.0f * (float)t + 1.0f) - 1.0f) * 0.5f);
        while ((bx + 1) * (bx + 2) / 2 <= t) ++bx;
        while (bx * (bx + 1) / 2 > t) --bx;
        byy = t - bx * (bx + 1) / 2;          // byy <= bx
    } else {
        bx = blockIdx.x; byy = blockIdx.y;
    }
    int tid  = threadIdx.x;
    int lane = tid & 63;
    int w    = tid >> 6;
    int rowBase = r0 + byy * STILE;
    int colBase = bx * STILE;
    int wrow = (w >> 2) * 128;          // 0 or 128
    int wcol = (w & 3) * 64;            // 0,64,128,192

    f32x4 acc[8][4];
    #pragma unroll
    for (int m = 0; m < 8; ++m)
        #pragma unroll
        for (int n = 0; n < 4; ++n)
            acc[m][n] = (f32x4){0.f, 0.f, 0.f, 0.f};

    // staging slots (16B each): call0 slot = tid (rows 0..127),
    // call1 slot = tid+512 (rows 128..255); 4 granules/row, swizzled source.
    int s0 = tid;
    int s1 = tid + 512;
    int r0s = s0 >> 2, g0s = s0 & 3, d0s = (g0s - (r0s >> 1)) & 3;
    int r1s = s1 >> 2, g1s = s1 & 3, d1s = (g1s - (r1s >> 1)) & 3;
    const unsigned short* gA0 = xb + (size_t)(rowBase + r0s) * INCH + d0s * 8;
    const unsigned short* gA1 = xb + (size_t)(rowBase + r1s) * INCH + d1s * 8;
    const unsigned short* gB0 = xb + (size_t)(colBase + r0s) * INCH + d0s * 8;
    const unsigned short* gB1 = xb + (size_t)(colBase + r1s) * INCH + d1s * 8;
    int ldsc0 = w * 512;                // halfword index, call 0
    int ldsc1 = 4096 + w * 512;         // call 1

    int kg  = lane >> 4;
    int arq = lane & 15;

    // prologue: stage K-step 0 into buf 0
    gload16(gA0, &smem.s.A[0][ldsc0]); gload16(gA1, &smem.s.A[0][ldsc1]);
    gload16(gB0, &smem.s.B[0][ldsc0]); gload16(gB1, &smem.s.B[0][ldsc1]);
    __syncthreads();

    for (int t = 0; t < 32; ++t) {
        int cur = t & 1;
        if (t < 31) {
            int k0 = (t + 1) * 32;
            gload16(gA0 + k0, &smem.s.A[cur ^ 1][ldsc0]);
            gload16(gA1 + k0, &smem.s.A[cur ^ 1][ldsc1]);
            gload16(gB0 + k0, &smem.s.B[cur ^ 1][ldsc0]);
            gload16(gB1 + k0, &smem.s.B[cur ^ 1][ldsc1]);
        }
        bf16x8 bfr[4];
        #pragma unroll
        for (int n = 0; n < 4; ++n) {
            int br = wcol + n * 16 + arq;
            int gp = (kg + (br >> 1)) & 3;
            bfr[n] = __builtin_bit_cast(bf16x8, *(const uint4*)&smem.s.B[cur][br * 32 + gp * 8]);
        }
        #pragma unroll
        for (int m = 0; m < 8; ++m) {
            int ar = wrow + m * 16 + arq;
            int gp = (kg + (ar >> 1)) & 3;
            bf16x8 af = __builtin_bit_cast(bf16x8, *(const uint4*)&smem.s.A[cur][ar * 32 + gp * 8]);
            #pragma unroll
            for (int n = 0; n < 4; ++n)
                acc[m][n] = __builtin_amdgcn_mfma_f32_16x16x32_bf16(af, bfr[n],
                                                                    acc[m][n], 0, 0, 0);
        }
        __syncthreads();
    }

    int rg = lane >> 4;
    // direct-orientation writes
    #pragma unroll
    for (int m = 0; m < 8; ++m) {
        int rloc = wrow + m * 16 + rg * 4;          // tile-local row
        int rl = byy * STILE + rloc;                // chunk-local row
        float sa0 = sq[rowBase + rloc + 0], sa1 = sq[rowBase + rloc + 1];
        float sa2 = sq[rowBase + rloc + 2], sa3 = sq[rowBase + rloc + 3];
        #pragma unroll
        for (int n = 0; n < 4; ++n) {
            int cl = wcol + n * 16 + arq;
            int c = colBase + cl;
            float sb = sq[c];
            _Float16 h0 = (_Float16)fmaxf((sa0 + sb - 2.f * acc[m][n][0]) * 0.25f, 0.f);
            _Float16 h1 = (_Float16)fmaxf((sa1 + sb - 2.f * acc[m][n][1]) * 0.25f, 0.f);
            _Float16 h2 = (_Float16)fmaxf((sa2 + sb - 2.f * acc[m][n][2]) * 0.25f, 0.f);
            _Float16 h3 = (_Float16)fmaxf((sa3 + sb - 2.f * acc[m][n][3]) * 0.25f, 0.f);
            _Float16* dp = Dh + (size_t)rl * NPTS + c;
            dp[0 * NPTS] = h0;
            dp[1 * NPTS] = h1;
            dp[2 * NPTS] = h2;
            dp[3 * NPTS] = h3;
        }
    }

    // transposed tile (off-diagonal), two 128-col passes through LDS
    if (SYM && (byy != bx)) {
        #pragma unroll
        for (int ch2 = 0; ch2 < 2; ++ch2) {
            __syncthreads();   // WAR: staging / previous-pass reads done
            if ((wcol >> 7) == ch2) {
                #pragma unroll
                for (int m = 0; m < 8; ++m) {
                    int rloc = wrow + m * 16 + rg * 4;
                    float sa0 = sq[rowBase + rloc + 0], sa1 = sq[rowBase + rloc + 1];
                    float sa2 = sq[rowBase + rloc + 2], sa3 = sq[rowBase + rloc + 3];
                    #pragma unroll
                    for (int n = 0; n < 4; ++n) {
                        int cl2 = (wcol & 127) + n * 16 + arq;
                        float sb = sq[colBase + ch2 * 128 + cl2];
                        f16x4 tv;
                        tv[0] = (_Float16)fmaxf((sa0 + sb - 2.f * acc[m][n][0]) * 0.25f, 0.f);
                        tv[1] = (_Float16)fmaxf((sa1 + sb - 2.f * acc[m][n][1]) * 0.25f, 0.f);
                        tv[2] = (_Float16)fmaxf((sa2 + sb - 2.f * acc[m][n][2]) * 0.25f, 0.f);
                        tv[3] = (_Float16)fmaxf((sa3 + sb - 2.f * acc[m][n][3]) * 0.25f, 0.f);
                        *(f16x4*)&smem.T[cl2 * 264 + rloc] = tv;
                    }
                }
            }
            __syncthreads();
            int cl2 = tid >> 2, seg = tid & 3;
            const unsigned short* src = (const unsigned short*)&smem.T[cl2 * 264 + seg * 64];
            unsigned short* gdst = (unsigned short*)Dh +
                                   (size_t)(colBase + ch2 * 128 + cl2) * NPTS +
                                   byy * STILE + seg * 64;
            #pragma unroll
            for (int i = 0; i < 8; ++i)
                *(uint4*)(gdst + i * 8) = *(const uint4*)(src + i * 8);
        }
    }
}

// ---------------------------------------------------------------------------
// Per row: exact top-16 (on f16 keys) candidate indices.
// One WAVE per row, zero barriers. All stored f16 >= 0 -> raw bits sortable.
// ---------------------------------------------------------------------------
__global__ __launch_bounds__(256) void topk16_kernel(const _Float16* __restrict__ Dh,
                                                     int* __restrict__ cand, int r0) {
    int wid  = threadIdx.x >> 6;
    int lane = threadIdx.x & 63;
    int row  = blockIdx.x * 4 + wid;
    const unsigned short* dr = (const unsigned short*)(Dh + (size_t)row * NPTS);

    unsigned kv[16];
    #pragma unroll
    for (int p = 0; p < 16; ++p) kv[p] = 0xffffffffu;

    for (int g = 0; g < 16; ++g) {
        int j0 = (g * 64 + lane) * 8;
        us8 v = *(const us8*)(dr + j0);
        unsigned s[8];
        #pragma unroll
        for (int e = 0; e < 8; ++e)
            s[e] = ((unsigned)v[e] << 13) | (unsigned)(j0 + e);
        CE32(s[0],s[1]); CE32(s[2],s[3]); CE32(s[4],s[5]); CE32(s[6],s[7]);
        CE32(s[0],s[2]); CE32(s[1],s[3]); CE32(s[4],s[6]); CE32(s[5],s[7]);
        CE32(s[1],s[2]); CE32(s[5],s[6]);
        CE32(s[0],s[4]); CE32(s[1],s[5]); CE32(s[2],s[6]); CE32(s[3],s[7]);
        CE32(s[2],s[4]); CE32(s[3],s[5]);
        CE32(s[1],s[2]); CE32(s[3],s[4]); CE32(s[5],s[6]);

        if (s[0] < kv[15]) {
            unsigned M[16];
            #pragma unroll
            for (int q = 0; q < 8; ++q) M[q] = kv[q];
            #pragma unroll
            for (int q = 8; q < 16; ++q) M[q] = min(kv[q], s[15 - q]);
            #pragma unroll
            for (int d = 8; d; d >>= 1)
                #pragma unroll
                for (int q = 0; q < 16; ++q)
                    if (!(q & d)) CE32(M[q], M[q + d]);
            #pragma unroll
            for (int q = 0; q < 16; ++q) kv[q] = M[q];
        }
    }

    #pragma unroll
    for (int st = 0; st < 6; ++st) {
        unsigned M[16];
        #pragma unroll
        for (int q = 0; q < 16; ++q) {
            unsigned pv = (unsigned)__shfl_xor((int)kv[15 - q], 1 << st);
            M[q] = min(kv[q], pv);
        }
        #pragma unroll
        for (int d = 8; d; d >>= 1)
            #pragma unroll
            for (int q = 0; q < 16; ++q)
                if (!(q & d)) CE32(M[q], M[q + d]);
        #pragma unroll
        for (int q = 0; q < 16; ++q) kv[q] = M[q];
    }

    if (lane == 0) {
        #pragma unroll
        for (int r = 0; r < 16; ++r)
            cand[(size_t)(r0 + row) * NCAND + r] = (int)(kv[r] & 0x1fffu);
    }
}

// ---------------------------------------------------------------------------
// Exact fp32 rescore: 16 candidates x 16 lanes, x-row staged in LDS.
// Emits nn (stride NNS) + Dv counts.
// ---------------------------------------------------------------------------
__global__ __launch_bounds__(256) void rescore_kernel(const float* __restrict__ x,
                                                      const float* __restrict__ sq,
                                                      const int* __restrict__ cand,
                                                      int* __restrict__ nn,
                                                      int* __restrict__ Dv) {
    __shared__ float xs[INCH];
    __shared__ unsigned long long keys[NCAND];
    int row = blockIdx.x;
    int tid = threadIdx.x;

    *(float4*)&xs[tid * 4] = *(const float4*)(x + (size_t)row * INCH + tid * 4);
    __syncthreads();

    int grp = tid >> 4;
    int q   = tid & 15;
    int cnd = cand[(size_t)row * NCAND + grp];
    const float4* cp = (const float4*)(x + (size_t)cnd * INCH);
    float dp = 0.f;
    #pragma unroll
    for (int i = 0; i < 16; ++i) {
        int idx = i * 16 + q;
        float4 a = *(const float4*)&xs[idx * 4];
        float4 b = cp[idx];
        dp += a.x * b.x + a.y * b.y + a.z * b.z + a.w * b.w;
    }
    #pragma unroll
    for (int o = 8; o; o >>= 1) dp += __shfl_xor(dp, o);
    if (q == 0) {
        float d = sq[row] + sq[cnd] - 2.f * dp;
        unsigned u = __float_as_uint(d);
        u = (u & 0x80000000u) ? ~u : (u | 0x80000000u);
        keys[grp] = ((unsigned long long)u << 32) | (unsigned)cnd;
    }
    __syncthreads();

    if (tid < 64) {
        int lane = tid;
        unsigned long long v = (lane < NCAND) ? keys[lane] : ~0ull;
        #pragma unroll
        for (int k = 2; k <= 64; k <<= 1) {
            #pragma unroll
            for (int j = k >> 1; j > 0; j >>= 1) {
                unsigned long long pv = __shfl_xor(v, j);
                bool lower = (lane & j) == 0;
                bool asc   = (lane & k) == 0;
                unsigned long long mn = v < pv ? v : pv;
                unsigned long long mx = v < pv ? pv : v;
                v = (lower == asc) ? mn : mx;
            }
        }
        if (lane < KNN) {
            int idx = (int)(v & 0xffffffffu);
            nn[(size_t)row * NNS + lane] = idx;
            atomicAdd(&Dv[idx], 1);
        }
    }
}

// ---------------------------------------------------------------------------
// bf16 MFMA GEMM:  C[M x 128] = A[M x KD] @ Bt[128 x KD]^T
// ---------------------------------------------------------------------------
__global__ __launch_bounds__(256) void mfma_gemm_kernel(const unsigned short* __restrict__ A,
                                                        const unsigned short* __restrict__ Bt,
                                                        float* __restrict__ C,
                                                        int KD, int nk) {
    __shared__ unsigned short Asm[2][4096];
    __shared__ unsigned short Bsm[2][4096];
    int tid  = threadIdx.x;
    int lane = tid & 63;
    int w    = tid >> 6;
    int rowBase = blockIdx.x * 128;
    int wrow = (w >> 1) * 64, wcol = (w & 1) * 64;

    f32x4 acc[4][4];
    #pragma unroll
    for (int m = 0; m < 4; ++m)
        #pragma unroll
        for (int n = 0; n < 4; ++n)
            acc[m][n] = (f32x4){0.f, 0.f, 0.f, 0.f};

    int s0 = w * 128 + lane;
    int s1 = s0 + 64;
    int r0s = s0 >> 2, g0s = s0 & 3, d0s = (g0s - (r0s >> 1)) & 3;
    int r1s = s1 >> 2, g1s = s1 & 3, d1s = (g1s - (r1s >> 1)) & 3;
    const unsigned short* gA0 = A + (size_t)(rowBase + r0s) * KD + d0s * 8;
    const unsigned short* gA1 = A + (size_t)(rowBase + r1s) * KD + d1s * 8;
    const unsigned short* gB0 = Bt + (size_t)r0s * KD + d0s * 8;
    const unsigned short* gB1 = Bt + (size_t)r1s * KD + d1s * 8;
    int ldsc0 = w * 1024;
    int ldsc1 = w * 1024 + 512;

    int kg = lane >> 4;
    int arq = lane & 15;

    gload16(gA0, &Asm[0][ldsc0]); gload16(gA1, &Asm[0][ldsc1]);
    gload16(gB0, &Bsm[0][ldsc0]); gload16(gB1, &Bsm[0][ldsc1]);
    __syncthreads();

    for (int t = 0; t < nk; ++t) {
        int cur = t & 1;
        if (t < nk - 1) {
            int k0 = (t + 1) * 32;
            gload16(gA0 + k0, &Asm[cur ^ 1][ldsc0]);
            gload16(gA1 + k0, &Asm[cur ^ 1][ldsc1]);
            gload16(gB0 + k0, &Bsm[cur ^ 1][ldsc0]);
            gload16(gB1 + k0, &Bsm[cur ^ 1][ldsc1]);
        }
        bf16x8 af[4], bfr[4];
        #pragma unroll
        for (int m = 0; m < 4; ++m) {
            int ar = wrow + m * 16 + arq;
            int gp = (kg + (ar >> 1)) & 3;
            af[m] = __builtin_bit_cast(bf16x8, *(const uint4*)&Asm[cur][ar * 32 + gp * 8]);
        }
        #pragma unroll
        for (int n = 0; n < 4; ++n) {
            int br = wcol + n * 16 + arq;
            int gp = (kg + (br >> 1)) & 3;
            bfr[n] = __builtin_bit_cast(bf16x8, *(const uint4*)&Bsm[cur][br * 32 + gp * 8]);
        }
        #pragma unroll
        for (int m = 0; m < 4; ++m)
            #pragma unroll
            for (int n = 0; n < 4; ++n)
                acc[m][n] = __builtin_amdgcn_mfma_f32_16x16x32_bf16(af[m], bfr[n],
                                                                    acc[m][n], 0, 0, 0);
        __syncthreads();
    }

    int rg = lane >> 4;
    #pragma unroll
    for (int m = 0; m < 4; ++m) {
        int rl = rowBase + wrow + m * 16 + rg * 4;
        #pragma unroll
        for (int n = 0; n < 4; ++n) {
            int c = wcol + n * 16 + (lane & 15);
            float* cp = C + (size_t)rl * FDIM + c;
            cp[0 * FDIM] = acc[m][n][0];
            cp[1 * FDIM] = acc[m][n][1];
            cp[2 * FDIM] = acc[m][n][2];
            cp[3 * FDIM] = acc[m][n][3];
        }
    }
}

// ---------------------------------------------------------------------------
// Fused edge mean + scatter  (nn stride NNS, aligned)
// ---------------------------------------------------------------------------
__global__ __launch_bounds__(256) void edge_scatter_kernel(const float* __restrict__ t,
                                                           const int* __restrict__ nn,
                                                           float* __restrict__ acc) {
    int eid = blockIdx.x * 2 + (threadIdx.x >> 7);
    int c = threadIdx.x & 127;
    const int* nnr = nn + (size_t)eid * NNS;
    int idx[KNN];
    #pragma unroll
    for (int k = 0; k < KNN; ++k) idx[k] = nnr[k];
    float s = 0.f;
    #pragma unroll
    for (int k = 0; k < KNN; ++k)
        s += t[(size_t)idx[k] * FDIM + c];
    s *= (1.f / (float)KNN);
    #pragma unroll
    for (int k = 0; k < KNN; ++k)
        atomicAdd(&acc[(size_t)idx[k] * FDIM + c], s);
}

// ---------------------------------------------------------------------------
// layer-0 finish: node_ft -> bf16, and ZEROES acc for the next scatter
// ---------------------------------------------------------------------------
__global__ __launch_bounds__(256) void finish_kernel(float* __restrict__ acc,
                                                     const int* __restrict__ Dv,
                                                     const float* __restrict__ bias,
                                                     unsigned short* __restrict__ outb) {
    int v = blockIdx.x * 2 + (threadIdx.x >> 7);
    int c = threadIdx.x & 127;
    int cnt = Dv[v];
    float dn = cnt > 1 ? (float)cnt : 1.f;
    size_t o = (size_t)v * FDIM + c;
    float s = acc[o] / dn + bias[c];
    acc[o] = 0.f;                       // reset for layer-1 scatter
    s = (s >= 0.f) ? s : 0.01f * s;
    outb[o] = f2bf(s);
}

// ---------------------------------------------------------------------------
// layer-1 finish fused with pooling partials: 64 blocks x 128 rows.
// ---------------------------------------------------------------------------
__global__ __launch_bounds__(256) void finish_pool_kernel(const float* __restrict__ acc,
                                                          const int* __restrict__ Dv,
                                                          const float* __restrict__ bias,
                                                          float* __restrict__ out,
                                                          float* __restrict__ part) {
    int c = threadIdx.x & 127;
    int half = threadIdx.x >> 7;
    int r0 = blockIdx.x * 128 + half;
    float b = bias[c];
    float ps = 0.f;
    for (int i = 0; i < 64; ++i) {
        int v = r0 + 2 * i;
        int cnt = Dv[v];
        float dn = cnt > 1 ? (float)cnt : 1.f;
        float s = acc[(size_t)v * FDIM + c] / dn + b;
        s = (s >= 0.f) ? s : 0.01f * s;
        out[(size_t)v * FDIM + c] = s;
        ps += s;
    }
    part[(size_t)(blockIdx.x * 2 + half) * FDIM + c] = ps;
}

__global__ __launch_bounds__(128) void final_kernel(const float* __restrict__ part,
                                                    const float* __restrict__ fcw,
                                                    const float* __restrict__ fcb,
                                                    float* __restrict__ out) {
    __shared__ float pool[FDIM];
    int c = threadIdx.x;
    float s = 0.f;
    for (int i = 0; i < 128; ++i)
        s += part[(size_t)i * FDIM + c];
    s *= (1.f / (float)NPTS);
    out[2 + (size_t)NPTS * FDIM + c] = s;
    pool[c] = s;
    __syncthreads();
    if (c < 2) {
        float z = fcb[c];
        for (int k = 0; k < FDIM; ++k)
            z += pool[k] * fcw[c * FDIM + k];
        out[c] = 1.f / (1.f + expf(-z));
    }
}

// ---------------------------------------------------------------------------
extern "C" void kernel_launch(void* const* d_in, const int* in_sizes, int n_in,
                              void* d_out, int out_size, void* d_ws, size_t ws_size,
                              hipStream_t stream) {
    const float* x   = (const float*)d_in[0];
    const float* th0 = (const float*)d_in[1];
    const float* b0  = (const float*)d_in[2];
    const float* th1 = (const float*)d_in[3];
    const float* b1  = (const float*)d_in[4];
    const float* fcw = (const float*)d_in[5];
    const float* fcb = (const float*)d_in[6];
    float* out = (float*)d_out;

    char* w = (char*)d_ws;
    size_t off = 0;
    auto alloc = [&](size_t bytes) -> void* {
        void* p = w + off;
        off = (off + bytes + 255) & ~(size_t)255;
        return p;
    };
    float* sq    = (float*)alloc(NPTS * 4);
    int*   nn    = (int*)  alloc(NPTS * NNS * 4);
    int*   Dv    = (int*)  alloc(NPTS * 4);
    int*   cand  = (int*)  alloc((size_t)NPTS * NCAND * 4);
    float* tbuf  = (float*)alloc((size_t)NPTS * FDIM * 4);
    float* accb  = (float*)alloc((size_t)NPTS * FDIM * 4);
    float* part  = (float*)alloc(128 * FDIM * 4);
    unsigned short* xbf   = (unsigned short*)alloc((size_t)NPTS * INCH * 2);
    unsigned short* hbufb = (unsigned short*)alloc((size_t)NPTS * FDIM * 2);
    unsigned short* th0t  = (unsigned short*)alloc((size_t)FDIM * INCH * 2);
    unsigned short* th1t  = (unsigned short*)alloc((size_t)FDIM * FDIM * 2);

    size_t rem = ws_size > off ? ws_size - off : 0;
    long long chMax = (long long)(rem / ((size_t)NPTS * 2));
    int CH = (int)(chMax > 8192 ? 8192 : chMax);
    CH &= ~255;
    if (CH < 256) CH = 256;
    _Float16* Dh = (_Float16*)(w + off);

    hipMemsetAsync(Dv, 0, NPTS * 4, stream);
    prep_kernel<<<NPTS / 4, 256, 0, stream>>>(x, sq, xbf);
    thT_kernel<<<dim3(INCH / 64, 2), 256, 0, stream>>>(th0, th0t, INCH);
    thT_kernel<<<dim3(FDIM / 64, 2), 256, 0, stream>>>(th1, th1t, FDIM);

    if (CH >= NPTS) {
        mfma_dist_kernel<true><<<NBLK2, 512, 0, stream>>>(xbf, sq, Dh, 0);
        topk16_kernel<<<NPTS / 4, 256, 0, stream>>>(Dh, cand, 0);
    } else {
        for (int r0 = 0; r0 < NPTS; r0 += CH) {
            int ch = NPTS - r0 < CH ? NPTS - r0 : CH;
            mfma_dist_kernel<false><<<dim3(NT2, ch / STILE), 512, 0, stream>>>(xbf, sq, Dh, r0);
            topk16_kernel<<<ch / 4, 256, 0, stream>>>(Dh, cand, r0);
        }
    }

    rescore_kernel<<<NPTS, 256, 0, stream>>>(x, sq, cand, nn, Dv);

    // layer 0 (bf16 MFMA gemm)
    mfma_gemm_kernel<<<NPTS / 128, 256, 0, stream>>>(xbf, th0t, tbuf, INCH, INCH / 32);
    hipMemsetAsync(accb, 0, (size_t)NPTS * FDIM * 4, stream);
    edge_scatter_kernel<<<NPTS / 2, 256, 0, stream>>>(tbuf, nn, accb);
    finish_kernel<<<NPTS / 2, 256, 0, stream>>>(accb, Dv, b0, hbufb);

    // layer 1 -> feats into out+2, pooling partials fused
    mfma_gemm_kernel<<<NPTS / 128, 256, 0, stream>>>(hbufb, th1t, tbuf, FDIM, FDIM / 32);
    edge_scatter_kernel<<<NPTS / 2, 256, 0, stream>>>(tbuf, nn, accb);
    finish_pool_kernel<<<64, 256, 0, stream>>>(accb, Dv, b1, out + 2, part);

    final_kernel<<<1, 128, 0, stream>>>(part, fcw, fcb, out);
}

// Round 14
// 422.949 us; speedup vs baseline: 1.0489x; 1.0489x over previous
//
#include <hip/hip_runtime.h>
#include <math.h>

#define NPTS  8192
#define INCH  1024
#define FDIM  128
#define KNN   10
#define NCAND 16
#define NNS   16              // nn row stride (padded)
#define NTILE (NPTS / 128)   // 64
#define NBLK  (NTILE * (NTILE + 1) / 2)   // 2080 triangle blocks

typedef __attribute__((ext_vector_type(8))) __bf16          bf16x8;
typedef __attribute__((ext_vector_type(4))) float           f32x4;
typedef __attribute__((ext_vector_type(8))) unsigned short  us8;
typedef __attribute__((ext_vector_type(4))) unsigned short  us4;
typedef __attribute__((ext_vector_type(4))) _Float16        f16x4;

// u32 compare-exchange: a=min, b=max  (v_min_u32 + v_max_u32)
#define CE32(a,b) do { unsigned lo_ = min((a),(b)); unsigned hi_ = max((a),(b)); \
                       (a)=lo_; (b)=hi_; } while(0)

__device__ __forceinline__ unsigned short f2bf(float f) {
    unsigned u = __float_as_uint(f);
    return (unsigned short)((u + 0x7fffu + ((u >> 16) & 1u)) >> 16);
}

// async global->LDS, 16 bytes per lane (dest = wave-uniform base + lane*16)
__device__ __forceinline__ void gload16(const void* g, void* l) {
    __builtin_amdgcn_global_load_lds(
        (const __attribute__((address_space(1))) unsigned int*)g,
        (__attribute__((address_space(3))) unsigned int*)l, 16, 0, 0);
}

// ---------------------------------------------------------------------------
// prep: sq[i] = sum x[i][d]^2 (bit-identical order) AND xb = bf16(x).
// ---------------------------------------------------------------------------
__global__ __launch_bounds__(256) void prep_kernel(const float* __restrict__ x,
                                                   float* __restrict__ sq,
                                                   unsigned short* __restrict__ xb) {
    int wave = threadIdx.x >> 6;
    int lane = threadIdx.x & 63;
    int row  = blockIdx.x * 4 + wave;
    const float4* xr = (const float4*)(x + (size_t)row * INCH);
    unsigned short* xo = xb + (size_t)row * INCH;
    float s = 0.f;
    #pragma unroll
    for (int i = 0; i < 4; ++i) {
        float4 v = xr[lane + i * 64];
        s += v.x * v.x + v.y * v.y + v.z * v.z + v.w * v.w;
        us4 o; o[0] = f2bf(v.x); o[1] = f2bf(v.y); o[2] = f2bf(v.z); o[3] = f2bf(v.w);
        *(us4*)(xo + (size_t)(lane + i * 64) * 4) = o;
    }
    #pragma unroll
    for (int o = 32; o; o >>= 1) s += __shfl_xor(s, o);
    if (lane == 0) sq[row] = s;
}

// ---------------------------------------------------------------------------
// theta transpose+convert: th[K][128] f32 -> out[128][K] bf16 (64x64 LDS tiles)
// ---------------------------------------------------------------------------
__global__ __launch_bounds__(256) void thT_kernel(const float* __restrict__ th,
                                                  unsigned short* __restrict__ out,
                                                  int K) {
    __shared__ unsigned short T[64][68];
    int k0 = blockIdx.x * 64;
    int n0 = blockIdx.y * 64;
    int t = threadIdx.x;
    int r  = t >> 2;
    int cs = (t & 3) * 16;
    const float* src = th + (size_t)(k0 + r) * FDIM + n0 + cs;
    #pragma unroll
    for (int i = 0; i < 4; ++i) {
        float4 v = *(const float4*)(src + i * 4);
        us4 o; o[0] = f2bf(v.x); o[1] = f2bf(v.y); o[2] = f2bf(v.z); o[3] = f2bf(v.w);
        *(us4*)&T[r][cs + i * 4] = o;
    }
    __syncthreads();
    int n  = t >> 2;
    int ks = (t & 3) * 16;
    unsigned short* dst = out + (size_t)(n0 + n) * K + k0 + ks;
    #pragma unroll
    for (int i = 0; i < 16; ++i)
        dst[i] = T[ks + i][n];
}

// ---------------------------------------------------------------------------
// bf16 MFMA distance tile -> f16 ( max(d,0)*0.25 ) matrix.
// Round-14: REVERT to the round-11 winner (128x128 tile, 4 waves, 2-barrier
// double-buffer schedule, pre-swizzled-source linear LDS, XCD swizzle,
// padded-LDS transpose writeback).  Counted-vmcnt (r12: L2 thrash) and 256^2
// tile (r13: occupancy collapse) both falsified by counters.  Added T5
// s_setprio around the MFMA cluster (null on lockstep per m190; harmless).
// MFMA operand values / accumulation order bit-identical to rounds 5-13.
// ---------------------------------------------------------------------------
union SharedU {
    struct { unsigned short A[2][4096], B[2][4096]; } s;   // 32 KB staging
    _Float16 T[128 * 136];                                  // 34.8 KB transpose
};

template <bool SYM>
__global__ __launch_bounds__(256) void mfma_dist_kernel(const unsigned short* __restrict__ xb,
                                                        const float* __restrict__ sq,
                                                        _Float16* __restrict__ Dh,
                                                        int r0) {
    __shared__ SharedU smem;
    int bx, byy;
    if (SYM) {
        int b = blockIdx.x;
        int t = (b & 7) * (NBLK / 8) + (b >> 3);   // XCD swizzle (T1), 2080%8==0
        bx = (int)((sqrtf(8.0f * (float)t + 1.0f) - 1.0f) * 0.5f);
        while ((bx + 1) * (bx + 2) / 2 <= t) ++bx;
        while (bx * (bx + 1) / 2 > t) --bx;
        byy = t - bx * (bx + 1) / 2;          // byy <= bx
    } else {
        bx = blockIdx.x; byy = blockIdx.y;
    }
    int tid  = threadIdx.x;
    int lane = tid & 63;
    int w    = tid >> 6;
    int rowBase = r0 + byy * 128;
    int colBase = bx * 128;
    int wrow = (w >> 1) * 64, wcol = (w & 1) * 64;

    f32x4 acc[4][4];
    #pragma unroll
    for (int m = 0; m < 4; ++m)
        #pragma unroll
        for (int n = 0; n < 4; ++n)
            acc[m][n] = (f32x4){0.f, 0.f, 0.f, 0.f};

    int s0 = w * 128 + lane;
    int s1 = s0 + 64;
    int r0s = s0 >> 2, g0s = s0 & 3, d0s = (g0s - (r0s >> 1)) & 3;
    int r1s = s1 >> 2, g1s = s1 & 3, d1s = (g1s - (r1s >> 1)) & 3;
    const unsigned short* gA0 = xb + (size_t)(rowBase + r0s) * INCH + d0s * 8;
    const unsigned short* gA1 = xb + (size_t)(rowBase + r1s) * INCH + d1s * 8;
    const unsigned short* gB0 = xb + (size_t)(colBase + r0s) * INCH + d0s * 8;
    const unsigned short* gB1 = xb + (size_t)(colBase + r1s) * INCH + d1s * 8;
    int ldsc0 = w * 1024;
    int ldsc1 = w * 1024 + 512;

    int kg = lane >> 4;
    int arq = lane & 15;

    gload16(gA0, &smem.s.A[0][ldsc0]); gload16(gA1, &smem.s.A[0][ldsc1]);
    gload16(gB0, &smem.s.B[0][ldsc0]); gload16(gB1, &smem.s.B[0][ldsc1]);
    __syncthreads();

    #pragma unroll 2
    for (int t = 0; t < 32; ++t) {
        int cur = t & 1;
        if (t < 31) {
            int k0 = (t + 1) * 32;
            gload16(gA0 + k0, &smem.s.A[cur ^ 1][ldsc0]);
            gload16(gA1 + k0, &smem.s.A[cur ^ 1][ldsc1]);
            gload16(gB0 + k0, &smem.s.B[cur ^ 1][ldsc0]);
            gload16(gB1 + k0, &smem.s.B[cur ^ 1][ldsc1]);
        }
        bf16x8 af[4], bfr[4];
        #pragma unroll
        for (int m = 0; m < 4; ++m) {
            int ar = wrow + m * 16 + arq;
            int gp = (kg + (ar >> 1)) & 3;
            af[m] = __builtin_bit_cast(bf16x8, *(const uint4*)&smem.s.A[cur][ar * 32 + gp * 8]);
        }
        #pragma unroll
        for (int n = 0; n < 4; ++n) {
            int br = wcol + n * 16 + arq;
            int gp = (kg + (br >> 1)) & 3;
            bfr[n] = __builtin_bit_cast(bf16x8, *(const uint4*)&smem.s.B[cur][br * 32 + gp * 8]);
        }
        __builtin_amdgcn_s_setprio(1);
        #pragma unroll
        for (int m = 0; m < 4; ++m)
            #pragma unroll
            for (int n = 0; n < 4; ++n)
                acc[m][n] = __builtin_amdgcn_mfma_f32_16x16x32_bf16(af[m], bfr[n],
                                                                    acc[m][n], 0, 0, 0);
        __builtin_amdgcn_s_setprio(0);
        __syncthreads();
    }

    int rg = lane >> 4;
    bool doT = SYM && (byy != bx);
    #pragma unroll
    for (int m = 0; m < 4; ++m) {
        int rloc = wrow + m * 16 + rg * 4;
        int rl = byy * 128 + rloc;
        float sa0 = sq[r0 + rl + 0], sa1 = sq[r0 + rl + 1];
        float sa2 = sq[r0 + rl + 2], sa3 = sq[r0 + rl + 3];
        #pragma unroll
        for (int n = 0; n < 4; ++n) {
            int cl = wcol + n * 16 + (lane & 15);
            int c = colBase + cl;
            float sb = sq[c];
            _Float16 h0 = (_Float16)fmaxf((sa0 + sb - 2.f * acc[m][n][0]) * 0.25f, 0.f);
            _Float16 h1 = (_Float16)fmaxf((sa1 + sb - 2.f * acc[m][n][1]) * 0.25f, 0.f);
            _Float16 h2 = (_Float16)fmaxf((sa2 + sb - 2.f * acc[m][n][2]) * 0.25f, 0.f);
            _Float16 h3 = (_Float16)fmaxf((sa3 + sb - 2.f * acc[m][n][3]) * 0.25f, 0.f);
            _Float16* dp = Dh + (size_t)rl * NPTS + c;
            dp[0 * NPTS] = h0;
            dp[1 * NPTS] = h1;
            dp[2 * NPTS] = h2;
            dp[3 * NPTS] = h3;
            if (doT) {
                f16x4 tv; tv[0] = h0; tv[1] = h1; tv[2] = h2; tv[3] = h3;
                *(f16x4*)&smem.T[cl * 136 + rloc] = tv;
            }
        }
    }
    if (doT) {
        __syncthreads();
        int cl = tid >> 1, half = tid & 1;
        const unsigned short* src = (const unsigned short*)&smem.T[cl * 136 + half * 64];
        unsigned short* gdst = (unsigned short*)Dh +
                               (size_t)(colBase + cl) * NPTS + byy * 128 + half * 64;
        #pragma unroll
        for (int i = 0; i < 8; ++i)
            *(uint4*)(gdst + i * 8) = *(const uint4*)(src + i * 8);
    }
}

// ---------------------------------------------------------------------------
// Per row: exact top-16 (on f16 keys) candidate indices.
// One WAVE per row, zero barriers. All stored f16 >= 0 -> raw bits sortable.
// ---------------------------------------------------------------------------
__global__ __launch_bounds__(256) void topk16_kernel(const _Float16* __restrict__ Dh,
                                                     int* __restrict__ cand, int r0) {
    int wid  = threadIdx.x >> 6;
    int lane = threadIdx.x & 63;
    int row  = blockIdx.x * 4 + wid;
    const unsigned short* dr = (const unsigned short*)(Dh + (size_t)row * NPTS);

    unsigned kv[16];
    #pragma unroll
    for (int p = 0; p < 16; ++p) kv[p] = 0xffffffffu;

    for (int g = 0; g < 16; ++g) {
        int j0 = (g * 64 + lane) * 8;
        us8 v = *(const us8*)(dr + j0);
        unsigned s[8];
        #pragma unroll
        for (int e = 0; e < 8; ++e)
            s[e] = ((unsigned)v[e] << 13) | (unsigned)(j0 + e);
        CE32(s[0],s[1]); CE32(s[2],s[3]); CE32(s[4],s[5]); CE32(s[6],s[7]);
        CE32(s[0],s[2]); CE32(s[1],s[3]); CE32(s[4],s[6]); CE32(s[5],s[7]);
        CE32(s[1],s[2]); CE32(s[5],s[6]);
        CE32(s[0],s[4]); CE32(s[1],s[5]); CE32(s[2],s[6]); CE32(s[3],s[7]);
        CE32(s[2],s[4]); CE32(s[3],s[5]);
        CE32(s[1],s[2]); CE32(s[3],s[4]); CE32(s[5],s[6]);

        if (s[0] < kv[15]) {
            unsigned M[16];
            #pragma unroll
            for (int q = 0; q < 8; ++q) M[q] = kv[q];
            #pragma unroll
            for (int q = 8; q < 16; ++q) M[q] = min(kv[q], s[15 - q]);
            #pragma unroll
            for (int d = 8; d; d >>= 1)
                #pragma unroll
                for (int q = 0; q < 16; ++q)
                    if (!(q & d)) CE32(M[q], M[q + d]);
            #pragma unroll
            for (int q = 0; q < 16; ++q) kv[q] = M[q];
        }
    }

    #pragma unroll
    for (int st = 0; st < 6; ++st) {
        unsigned M[16];
        #pragma unroll
        for (int q = 0; q < 16; ++q) {
            unsigned pv = (unsigned)__shfl_xor((int)kv[15 - q], 1 << st);
            M[q] = min(kv[q], pv);
        }
        #pragma unroll
        for (int d = 8; d; d >>= 1)
            #pragma unroll
            for (int q = 0; q < 16; ++q)
                if (!(q & d)) CE32(M[q], M[q + d]);
        #pragma unroll
        for (int q = 0; q < 16; ++q) kv[q] = M[q];
    }

    if (lane == 0) {
        #pragma unroll
        for (int r = 0; r < 16; ++r)
            cand[(size_t)(r0 + row) * NCAND + r] = (int)(kv[r] & 0x1fffu);
    }
}

// ---------------------------------------------------------------------------
// Exact fp32 rescore: 16 candidates x 16 lanes, x-row staged in LDS.
// Emits nn (stride NNS) + Dv counts.
// ---------------------------------------------------------------------------
__global__ __launch_bounds__(256) void rescore_kernel(const float* __restrict__ x,
                                                      const float* __restrict__ sq,
                                                      const int* __restrict__ cand,
                                                      int* __restrict__ nn,
                                                      int* __restrict__ Dv) {
    __shared__ float xs[INCH];
    __shared__ unsigned long long keys[NCAND];
    int row = blockIdx.x;
    int tid = threadIdx.x;

    *(float4*)&xs[tid * 4] = *(const float4*)(x + (size_t)row * INCH + tid * 4);
    __syncthreads();

    int grp = tid >> 4;
    int q   = tid & 15;
    int cnd = cand[(size_t)row * NCAND + grp];
    const float4* cp = (const float4*)(x + (size_t)cnd * INCH);
    float dp = 0.f;
    #pragma unroll
    for (int i = 0; i < 16; ++i) {
        int idx = i * 16 + q;
        float4 a = *(const float4*)&xs[idx * 4];
        float4 b = cp[idx];
        dp += a.x * b.x + a.y * b.y + a.z * b.z + a.w * b.w;
    }
    #pragma unroll
    for (int o = 8; o; o >>= 1) dp += __shfl_xor(dp, o);
    if (q == 0) {
        float d = sq[row] + sq[cnd] - 2.f * dp;
        unsigned u = __float_as_uint(d);
        u = (u & 0x80000000u) ? ~u : (u | 0x80000000u);
        keys[grp] = ((unsigned long long)u << 32) | (unsigned)cnd;
    }
    __syncthreads();

    if (tid < 64) {
        int lane = tid;
        unsigned long long v = (lane < NCAND) ? keys[lane] : ~0ull;
        #pragma unroll
        for (int k = 2; k <= 64; k <<= 1) {
            #pragma unroll
            for (int j = k >> 1; j > 0; j >>= 1) {
                unsigned long long pv = __shfl_xor(v, j);
                bool lower = (lane & j) == 0;
                bool asc   = (lane & k) == 0;
                unsigned long long mn = v < pv ? v : pv;
                unsigned long long mx = v < pv ? pv : v;
                v = (lower == asc) ? mn : mx;
            }
        }
        if (lane < KNN) {
            int idx = (int)(v & 0xffffffffu);
            nn[(size_t)row * NNS + lane] = idx;
            atomicAdd(&Dv[idx], 1);
        }
    }
}

// ---------------------------------------------------------------------------
// bf16 MFMA GEMM:  C[M x 128] = A[M x KD] @ Bt[128 x KD]^T
// ---------------------------------------------------------------------------
__global__ __launch_bounds__(256) void mfma_gemm_kernel(const unsigned short* __restrict__ A,
                                                        const unsigned short* __restrict__ Bt,
                                                        float* __restrict__ C,
                                                        int KD, int nk) {
    __shared__ unsigned short Asm[2][4096];
    __shared__ unsigned short Bsm[2][4096];
    int tid  = threadIdx.x;
    int lane = tid & 63;
    int w    = tid >> 6;
    int rowBase = blockIdx.x * 128;
    int wrow = (w >> 1) * 64, wcol = (w & 1) * 64;

    f32x4 acc[4][4];
    #pragma unroll
    for (int m = 0; m < 4; ++m)
        #pragma unroll
        for (int n = 0; n < 4; ++n)
            acc[m][n] = (f32x4){0.f, 0.f, 0.f, 0.f};

    int s0 = w * 128 + lane;
    int s1 = s0 + 64;
    int r0s = s0 >> 2, g0s = s0 & 3, d0s = (g0s - (r0s >> 1)) & 3;
    int r1s = s1 >> 2, g1s = s1 & 3, d1s = (g1s - (r1s >> 1)) & 3;
    const unsigned short* gA0 = A + (size_t)(rowBase + r0s) * KD + d0s * 8;
    const unsigned short* gA1 = A + (size_t)(rowBase + r1s) * KD + d1s * 8;
    const unsigned short* gB0 = Bt + (size_t)r0s * KD + d0s * 8;
    const unsigned short* gB1 = Bt + (size_t)r1s * KD + d1s * 8;
    int ldsc0 = w * 1024;
    int ldsc1 = w * 1024 + 512;

    int kg = lane >> 4;
    int arq = lane & 15;

    gload16(gA0, &Asm[0][ldsc0]); gload16(gA1, &Asm[0][ldsc1]);
    gload16(gB0, &Bsm[0][ldsc0]); gload16(gB1, &Bsm[0][ldsc1]);
    __syncthreads();

    for (int t = 0; t < nk; ++t) {
        int cur = t & 1;
        if (t < nk - 1) {
            int k0 = (t + 1) * 32;
            gload16(gA0 + k0, &Asm[cur ^ 1][ldsc0]);
            gload16(gA1 + k0, &Asm[cur ^ 1][ldsc1]);
            gload16(gB0 + k0, &Bsm[cur ^ 1][ldsc0]);
            gload16(gB1 + k0, &Bsm[cur ^ 1][ldsc1]);
        }
        bf16x8 af[4], bfr[4];
        #pragma unroll
        for (int m = 0; m < 4; ++m) {
            int ar = wrow + m * 16 + arq;
            int gp = (kg + (ar >> 1)) & 3;
            af[m] = __builtin_bit_cast(bf16x8, *(const uint4*)&Asm[cur][ar * 32 + gp * 8]);
        }
        #pragma unroll
        for (int n = 0; n < 4; ++n) {
            int br = wcol + n * 16 + arq;
            int gp = (kg + (br >> 1)) & 3;
            bfr[n] = __builtin_bit_cast(bf16x8, *(const uint4*)&Bsm[cur][br * 32 + gp * 8]);
        }
        #pragma unroll
        for (int m = 0; m < 4; ++m)
            #pragma unroll
            for (int n = 0; n < 4; ++n)
                acc[m][n] = __builtin_amdgcn_mfma_f32_16x16x32_bf16(af[m], bfr[n],
                                                                    acc[m][n], 0, 0, 0);
        __syncthreads();
    }

    int rg = lane >> 4;
    #pragma unroll
    for (int m = 0; m < 4; ++m) {
        int rl = rowBase + wrow + m * 16 + rg * 4;
        #pragma unroll
        for (int n = 0; n < 4; ++n) {
            int c = wcol + n * 16 + (lane & 15);
            float* cp = C + (size_t)rl * FDIM + c;
            cp[0 * FDIM] = acc[m][n][0];
            cp[1 * FDIM] = acc[m][n][1];
            cp[2 * FDIM] = acc[m][n][2];
            cp[3 * FDIM] = acc[m][n][3];
        }
    }
}

// ---------------------------------------------------------------------------
// Fused edge mean + scatter  (nn stride NNS, aligned)
// ---------------------------------------------------------------------------
__global__ __launch_bounds__(256) void edge_scatter_kernel(const float* __restrict__ t,
                                                           const int* __restrict__ nn,
                                                           float* __restrict__ acc) {
    int eid = blockIdx.x * 2 + (threadIdx.x >> 7);
    int c = threadIdx.x & 127;
    const int* nnr = nn + (size_t)eid * NNS;
    int idx[KNN];
    #pragma unroll
    for (int k = 0; k < KNN; ++k) idx[k] = nnr[k];
    float s = 0.f;
    #pragma unroll
    for (int k = 0; k < KNN; ++k)
        s += t[(size_t)idx[k] * FDIM + c];
    s *= (1.f / (float)KNN);
    #pragma unroll
    for (int k = 0; k < KNN; ++k)
        atomicAdd(&acc[(size_t)idx[k] * FDIM + c], s);
}

// ---------------------------------------------------------------------------
// layer-0 finish: node_ft -> bf16, and ZEROES acc for the next scatter
// ---------------------------------------------------------------------------
__global__ __launch_bounds__(256) void finish_kernel(float* __restrict__ acc,
                                                     const int* __restrict__ Dv,
                                                     const float* __restrict__ bias,
                                                     unsigned short* __restrict__ outb) {
    int v = blockIdx.x * 2 + (threadIdx.x >> 7);
    int c = threadIdx.x & 127;
    int cnt = Dv[v];
    float dn = cnt > 1 ? (float)cnt : 1.f;
    size_t o = (size_t)v * FDIM + c;
    float s = acc[o] / dn + bias[c];
    acc[o] = 0.f;                       // reset for layer-1 scatter
    s = (s >= 0.f) ? s : 0.01f * s;
    outb[o] = f2bf(s);
}

// ---------------------------------------------------------------------------
// layer-1 finish fused with pooling partials: 64 blocks x 128 rows.
// ---------------------------------------------------------------------------
__global__ __launch_bounds__(256) void finish_pool_kernel(const float* __restrict__ acc,
                                                          const int* __restrict__ Dv,
                                                          const float* __restrict__ bias,
                                                          float* __restrict__ out,
                                                          float* __restrict__ part) {
    int c = threadIdx.x & 127;
    int half = threadIdx.x >> 7;
    int r0 = blockIdx.x * 128 + half;
    float b = bias[c];
    float ps = 0.f;
    for (int i = 0; i < 64; ++i) {
        int v = r0 + 2 * i;
        int cnt = Dv[v];
        float dn = cnt > 1 ? (float)cnt : 1.f;
        float s = acc[(size_t)v * FDIM + c] / dn + b;
        s = (s >= 0.f) ? s : 0.01f * s;
        out[(size_t)v * FDIM + c] = s;
        ps += s;
    }
    part[(size_t)(blockIdx.x * 2 + half) * FDIM + c] = ps;
}

__global__ __launch_bounds__(128) void final_kernel(const float* __restrict__ part,
                                                    const float* __restrict__ fcw,
                                                    const float* __restrict__ fcb,
                                                    float* __restrict__ out) {
    __shared__ float pool[FDIM];
    int c = threadIdx.x;
    float s = 0.f;
    for (int i = 0; i < 128; ++i)
        s += part[(size_t)i * FDIM + c];
    s *= (1.f / (float)NPTS);
    out[2 + (size_t)NPTS * FDIM + c] = s;
    pool[c] = s;
    __syncthreads();
    if (c < 2) {
        float z = fcb[c];
        for (int k = 0; k < FDIM; ++k)
            z += pool[k] * fcw[c * FDIM + k];
        out[c] = 1.f / (1.f + expf(-z));
    }
}

// ---------------------------------------------------------------------------
extern "C" void kernel_launch(void* const* d_in, const int* in_sizes, int n_in,
                              void* d_out, int out_size, void* d_ws, size_t ws_size,
                              hipStream_t stream) {
    const float* x   = (const float*)d_in[0];
    const float* th0 = (const float*)d_in[1];
    const float* b0  = (const float*)d_in[2];
    const float* th1 = (const float*)d_in[3];
    const float* b1  = (const float*)d_in[4];
    const float* fcw = (const float*)d_in[5];
    const float* fcb = (const float*)d_in[6];
    float* out = (float*)d_out;

    char* w = (char*)d_ws;
    size_t off = 0;
    auto alloc = [&](size_t bytes) -> void* {
        void* p = w + off;
        off = (off + bytes + 255) & ~(size_t)255;
        return p;
    };
    float* sq    = (float*)alloc(NPTS * 4);
    int*   nn    = (int*)  alloc(NPTS * NNS * 4);
    int*   Dv    = (int*)  alloc(NPTS * 4);
    int*   cand  = (int*)  alloc((size_t)NPTS * NCAND * 4);
    float* tbuf  = (float*)alloc((size_t)NPTS * FDIM * 4);
    float* accb  = (float*)alloc((size_t)NPTS * FDIM * 4);
    float* part  = (float*)alloc(128 * FDIM * 4);
    unsigned short* xbf   = (unsigned short*)alloc((size_t)NPTS * INCH * 2);
    unsigned short* hbufb = (unsigned short*)alloc((size_t)NPTS * FDIM * 2);
    unsigned short* th0t  = (unsigned short*)alloc((size_t)FDIM * INCH * 2);
    unsigned short* th1t  = (unsigned short*)alloc((size_t)FDIM * FDIM * 2);

    size_t rem = ws_size > off ? ws_size - off : 0;
    long long chMax = (long long)(rem / ((size_t)NPTS * 2));
    int CH = (int)(chMax > 8192 ? 8192 : chMax);
    CH &= ~127;
    if (CH < 128) CH = 128;
    _Float16* Dh = (_Float16*)(w + off);

    hipMemsetAsync(Dv, 0, NPTS * 4, stream);
    prep_kernel<<<NPTS / 4, 256, 0, stream>>>(x, sq, xbf);
    thT_kernel<<<dim3(INCH / 64, 2), 256, 0, stream>>>(th0, th0t, INCH);
    thT_kernel<<<dim3(FDIM / 64, 2), 256, 0, stream>>>(th1, th1t, FDIM);

    if (CH >= NPTS) {
        mfma_dist_kernel<true><<<NBLK, 256, 0, stream>>>(xbf, sq, Dh, 0);
        topk16_kernel<<<NPTS / 4, 256, 0, stream>>>(Dh, cand, 0);
    } else {
        for (int r0 = 0; r0 < NPTS; r0 += CH) {
            int ch = NPTS - r0 < CH ? NPTS - r0 : CH;
            mfma_dist_kernel<false><<<dim3(NTILE, ch / 128), 256, 0, stream>>>(xbf, sq, Dh, r0);
            topk16_kernel<<<ch / 4, 256, 0, stream>>>(Dh, cand, r0);
        }
    }

    rescore_kernel<<<NPTS, 256, 0, stream>>>(x, sq, cand, nn, Dv);

    // layer 0 (bf16 MFMA gemm)
    mfma_gemm_kernel<<<NPTS / 128, 256, 0, stream>>>(xbf, th0t, tbuf, INCH, INCH / 32);
    hipMemsetAsync(accb, 0, (size_t)NPTS * FDIM * 4, stream);
    edge_scatter_kernel<<<NPTS / 2, 256, 0, stream>>>(tbuf, nn, accb);
    finish_kernel<<<NPTS / 2, 256, 0, stream>>>(accb, Dv, b0, hbufb);

    // layer 1 -> feats into out+2, pooling partials fused
    mfma_gemm_kernel<<<NPTS / 128, 256, 0, stream>>>(hbufb, th1t, tbuf, FDIM, FDIM / 32);
    edge_scatter_kernel<<<NPTS / 2, 256, 0, stream>>>(tbuf, nn, accb);
    finish_pool_kernel<<<64, 256, 0, stream>>>(accb, Dv, b1, out + 2, part);

    final_kernel<<<1, 128, 0, stream>>>(part, fcw, fcb, out);
}